// Round 4
// baseline (821.579 us; speedup 1.0000x reference)
//
#include <hip/hip_runtime.h>

#define NN 10000
#define NE 640000
#define CH 128
#define NH 8
#define HD 16
#define BD 32
#define NEG 0.01f
#define SLOTS 160   // per-node edge-slot stride; deg ~ Poisson(64), P(>=160) ~ 1e-25
#define CSTR 32     // counts stride (ints): one counter per 128B (sector-safe)

#define GEMM_BLOCKS (NN / 16)            // 625 (16 rows per block)
#define HIST_BLOCKS 313                  // 8 edges per thread

typedef unsigned short u16;
using frag_ab = __attribute__((ext_vector_type(8))) short;  // 8 bf16 (4 VGPRs)
using frag_cd = __attribute__((ext_vector_type(4))) float;  // 4 fp32

// bf16 round-to-nearest-even
__device__ __forceinline__ u16 bf16h(float f) {
    unsigned b = __float_as_uint(f);
    b += 0x7fffu + ((b >> 16) & 1u);
    return (u16)(b >> 16);
}
__device__ __forceinline__ float bf2f(u16 h) {
    return __uint_as_float((unsigned)h << 16);
}

// DPP butterfly sum over each 16-lane row (one head = 16 channels): pure VALU.
template <int CTRL>
__device__ __forceinline__ float dpp_add(float x) {
    int v = __builtin_amdgcn_update_dpp(0, __float_as_int(x), CTRL, 0xF, 0xF, true);
    return x + __int_as_float(v);
}
__device__ __forceinline__ float sum16(float x) {
    x = dpp_add<0xB1>(x);   // quad_perm xor1
    x = dpp_add<0x4E>(x);   // quad_perm xor2
    x = dpp_add<0x141>(x);  // row_half_mirror
    x = dpp_add<0x140>(x);  // row_mirror
    return x;
}

// ---------------- K0: weight prep (48 blocks: 16 per matrix) -----------------
// Split W into bf16 hi/lo and pack into MFMA B-fragment order:
// Wfrag[(mat*2+hilo)*16384 + (nt*4+ks)*512 + lane*8 + i]
// where element (k,n): nt=n>>4, ks=k>>5, lane=((k&31)>>3)*16+(n&15), i=k&7.
__global__ __launch_bounds__(256) void wprep_kernel(
    const float* __restrict__ WQ, const float* __restrict__ WK,
    const float* __restrict__ WV, u16* __restrict__ Wfrag)
{
    int mat = blockIdx.x >> 4;
    int j0 = (blockIdx.x & 15) * 4;
    const float* W = mat == 0 ? WQ : (mat == 1 ? WK : WV);
    size_t mbase = (size_t)mat * 2 * 16384;
    int t = threadIdx.x;
    for (int j = j0; j < j0 + 4; ++j) {
        int lin = j * 256 + t;          // coalesced read
        int k = lin >> 7, n = lin & 127;
        float f = W[lin];
        u16 h = bf16h(f);
        u16 lo = bf16h(f - bf2f(h));
        int nt = n >> 4, ks = k >> 5, kk = k & 31;
        size_t o = (size_t)(nt * 4 + ks) * 512 + (size_t)(((kk >> 3) << 4) | (n & 15)) * 8 + (kk & 7);
        Wfrag[mbase + o] = h;
        Wfrag[mbase + 16384 + o] = lo;
    }
}

// ---------------- K1: MFMA projections + hist (fused, independent) -----------
// GEMM part (blocks 0..624): 16 node-rows/block; wave w handles column tiles
// {2w,2w+1} for Q,K,V. fp32 exactness via 3-term bf16 split: Ah*Wh+Ah*Wl+Al*Wh.
// HIST part (blocks 625..937): 8 edges/thread (8 independent atomic RTT chains
// in flight -> covers LLC atomic latency); counts padded 1/128B (CSTR).
__global__ __launch_bounds__(256) void gemm_hist_kernel(
    const float* __restrict__ senders, const float* __restrict__ receivers,
    const u16* __restrict__ Wfrag,
    float* __restrict__ Qn, unsigned* __restrict__ KVP,
    const int* __restrict__ eidx, int* __restrict__ counts,
    int2* __restrict__ es)
{
    if (blockIdx.x >= GEMM_BLOCKS) {
        int t = (blockIdx.x - GEMM_BLOCKS) * 256 + threadIdx.x;
        int e0 = t * 8;
        if (e0 < NE) {
            int4 da = *(const int4*)(eidx + NE + e0);
            int4 db = *(const int4*)(eidx + NE + e0 + 4);
            int4 sa = *(const int4*)(eidx + e0);
            int4 sb = *(const int4*)(eidx + e0 + 4);
            int r0 = atomicAdd(&counts[da.x * CSTR], 1);
            int r1 = atomicAdd(&counts[da.y * CSTR], 1);
            int r2 = atomicAdd(&counts[da.z * CSTR], 1);
            int r3 = atomicAdd(&counts[da.w * CSTR], 1);
            int r4 = atomicAdd(&counts[db.x * CSTR], 1);
            int r5 = atomicAdd(&counts[db.y * CSTR], 1);
            int r6 = atomicAdd(&counts[db.z * CSTR], 1);
            int r7 = atomicAdd(&counts[db.w * CSTR], 1);
            es[da.x * SLOTS + r0] = make_int2(e0,     sa.x);
            es[da.y * SLOTS + r1] = make_int2(e0 + 1, sa.y);
            es[da.z * SLOTS + r2] = make_int2(e0 + 2, sa.z);
            es[da.w * SLOTS + r3] = make_int2(e0 + 3, sa.w);
            es[db.x * SLOTS + r4] = make_int2(e0 + 4, sb.x);
            es[db.y * SLOTS + r5] = make_int2(e0 + 5, sb.y);
            es[db.z * SLOTS + r6] = make_int2(e0 + 6, sb.z);
            es[db.w * SLOTS + r7] = make_int2(e0 + 7, sb.w);
        }
        return;
    }

    int wave = threadIdx.x >> 6, l = threadIdx.x & 63;
    int r0 = blockIdx.x * 16;
    int arow = r0 + (l & 15);           // A-fragment row for this lane
    int kcol = (l >> 4) * 8;            // A-fragment k-offset within 32-k step

    // Load this strip's A rows (fp32) and split to bf16 hi/lo fragments.
    frag_ab Rh[4], Rl[4], Sh[4], Sl[4];
#pragma unroll
    for (int ks = 0; ks < 4; ++ks) {
        const float* rp = receivers + (size_t)arow * CH + ks * 32 + kcol;
        const float* sp = senders   + (size_t)arow * CH + ks * 32 + kcol;
        float4 ra = *(const float4*)rp, rb = *(const float4*)(rp + 4);
        float4 sa = *(const float4*)sp, sb = *(const float4*)(sp + 4);
        float rf[8] = {ra.x, ra.y, ra.z, ra.w, rb.x, rb.y, rb.z, rb.w};
        float sf[8] = {sa.x, sa.y, sa.z, sa.w, sb.x, sb.y, sb.z, sb.w};
#pragma unroll
        for (int i = 0; i < 8; ++i) {
            u16 rh = bf16h(rf[i]);  Rh[ks][i] = (short)rh;
            Rl[ks][i] = (short)bf16h(rf[i] - bf2f(rh));
            u16 sh = bf16h(sf[i]);  Sh[ks][i] = (short)sh;
            Sl[ks][i] = (short)bf16h(sf[i] - bf2f(sh));
        }
    }

    // W fragment loader: contiguous 16B per lane, fully coalesced, L2-hot.
    auto ldw = [&](int mat, int hilo, int nt, int ks) -> frag_ab {
        return *(const frag_ab*)(Wfrag + (size_t)(mat * 2 + hilo) * 16384
                                       + (size_t)(nt * 4 + ks) * 512 + l * 8);
    };

#pragma unroll
    for (int nts = 0; nts < 2; ++nts) {
        int nt = wave * 2 + nts;
        frag_cd aQ = {0.f, 0.f, 0.f, 0.f};
        frag_cd aK = {0.f, 0.f, 0.f, 0.f};
        frag_cd aV = {0.f, 0.f, 0.f, 0.f};
#pragma unroll
        for (int ks = 0; ks < 4; ++ks) {
            aQ = __builtin_amdgcn_mfma_f32_16x16x32_bf16(Rh[ks], ldw(0, 0, nt, ks), aQ, 0, 0, 0);
            aQ = __builtin_amdgcn_mfma_f32_16x16x32_bf16(Rh[ks], ldw(0, 1, nt, ks), aQ, 0, 0, 0);
            aQ = __builtin_amdgcn_mfma_f32_16x16x32_bf16(Rl[ks], ldw(0, 0, nt, ks), aQ, 0, 0, 0);
            aK = __builtin_amdgcn_mfma_f32_16x16x32_bf16(Sh[ks], ldw(1, 0, nt, ks), aK, 0, 0, 0);
            aK = __builtin_amdgcn_mfma_f32_16x16x32_bf16(Sh[ks], ldw(1, 1, nt, ks), aK, 0, 0, 0);
            aK = __builtin_amdgcn_mfma_f32_16x16x32_bf16(Sl[ks], ldw(1, 0, nt, ks), aK, 0, 0, 0);
            aV = __builtin_amdgcn_mfma_f32_16x16x32_bf16(Sh[ks], ldw(2, 0, nt, ks), aV, 0, 0, 0);
            aV = __builtin_amdgcn_mfma_f32_16x16x32_bf16(Sh[ks], ldw(2, 1, nt, ks), aV, 0, 0, 0);
            aV = __builtin_amdgcn_mfma_f32_16x16x32_bf16(Sl[ks], ldw(2, 0, nt, ks), aV, 0, 0, 0);
        }
        // D layout: col = lane&15, row = (lane>>4)*4 + j  [guide §3, m89-verified]
#pragma unroll
        for (int j = 0; j < 4; ++j) {
            int orow = r0 + (l >> 4) * 4 + j;
            int ocol = nt * 16 + (l & 15);
            size_t o = (size_t)orow * CH + ocol;
            Qn[o] = aQ[j];
            KVP[o] = (unsigned)bf16h(aK[j]) | ((unsigned)bf16h(aV[j]) << 16);
        }
    }
}

// ---------------- fused per-node edge loop (UNCHANGED except launch_bounds) --
// One WAVE per node, lane l owns channels l and l+64. 8-edge tiles; eattr
// rows via wave-uniform s_load. KV gather: ONE dword per (edge, lane, half).
// Do not reshape this loop (R8/R9/R11 prev-session regressions; R1-this-session
// edge-split regression). launch_bounds (256,4)->(256,8): VGPR=48 fits 64-cap;
// occupancy was the 40% idle cause (R3 model: 80us issue floor, 70us idle).
__global__ __launch_bounds__(256, 8) void fused_kernel(
    const int2* __restrict__ es, const int* __restrict__ counts,
    const float* __restrict__ eattr, const float* __restrict__ WE,
    const float* __restrict__ att, const float* __restrict__ Qn,
    const unsigned* __restrict__ KVP, float* __restrict__ out)
{
    int wave = threadIdx.x >> 6, l = threadIdx.x & 63;
    int n = blockIdx.x * 4 + wave;            // 2500 blocks * 4 waves = NN
    int start = n * SLOTS;
    int end = start + counts[n * CSTR];

    float rWE[2 * BD];
#pragma unroll
    for (int k = 0; k < BD; ++k) {
        rWE[k]      = WE[k * CH + l];
        rWE[BD + k] = WE[k * CH + 64 + l];
    }
#pragma unroll
    for (int k = 0; k < 2 * BD; ++k) asm volatile("" : "+v"(rWE[k]));

    float a0 = att[l], a1 = att[64 + l];
    float q0 = Qn[(size_t)n * CH + l], q1 = Qn[(size_t)n * CH + 64 + l];
    float acc0 = 0.f, acc1 = 0.f, sum0 = 0.f, sum1 = 0.f;

    for (int base = start; base < end; base += 8) {
        int m = end - base;                   // >=1
        int idx = base + (l & 7);
        if (idx >= end) idx = end - 1;
        int2 esv = es[idx];
#pragma unroll 8
        for (int t = 0; t < 8; ++t) {
            if (t >= m) break;                // wave-uniform
            int e   = __builtin_amdgcn_readlane(esv.x, t);
            int src = __builtin_amdgcn_readlane(esv.y, t);
            const float* __restrict__ row = eattr + (size_t)e * BD;
            size_t so = (size_t)src * CH;
            unsigned p0 = KVP[so + l];
            unsigned p1 = KVP[so + 64 + l];
            float kb0 = __uint_as_float(p0 << 16);
            float kb1 = __uint_as_float(p1 << 16);
            float vv0 = __uint_as_float(p0 & 0xffff0000u);
            float vv1 = __uint_as_float(p1 & 0xffff0000u);
            float ec0 = 0.f, ec1 = 0.f;
#pragma unroll
            for (int k = 0; k < BD; ++k) {
                float rv = row[k];            // uniform -> s_load
                ec0 = fmaf(rv, rWE[k],      ec0);
                ec1 = fmaf(rv, rWE[BD + k], ec1);
            }
            float h0 = q0 + kb0 + ec0; h0 = h0 > 0.f ? h0 : NEG * h0;
            float h1 = q1 + kb1 + ec1; h1 = h1 > 0.f ? h1 : NEG * h1;
            float t0 = sum16(a0 * h0);
            float t1 = sum16(a1 * h1);
            float e0 = __expf(t0), e1 = __expf(t1);
            sum0 += e0; acc0 = fmaf(e0, vv0, acc0);
            sum1 += e1; acc1 = fmaf(e1, vv1, acc1);
        }
    }
    out[(size_t)n * CH + l]      = (end > start) ? acc0 / sum0 : 0.f;
    out[(size_t)n * CH + 64 + l] = (end > start) ? acc1 / sum1 : 0.f;
}

extern "C" void kernel_launch(void* const* d_in, const int* in_sizes, int n_in,
                              void* d_out, int out_size, void* d_ws, size_t ws_size,
                              hipStream_t stream)
{
    const float* senders   = (const float*)d_in[0];
    const float* receivers = (const float*)d_in[1];
    const int*   eidx      = (const int*)d_in[2];
    const float* eattr     = (const float*)d_in[3];
    const float* WQ  = (const float*)d_in[4];
    const float* WK  = (const float*)d_in[5];
    const float* WV  = (const float*)d_in[6];
    const float* WE  = (const float*)d_in[7];
    const float* att = (const float*)d_in[8];
    float* out = (float*)d_out;

    char* ws = (char*)d_ws;
    size_t off = 0;
    auto alloc = [&](size_t bytes) -> void* {
        void* p = ws + off;
        off += (bytes + 255) & ~(size_t)255;
        return p;
    };
    // Qn 5.12 + KVP 5.12 + counts 1.28 + es 12.8 + Wfrag 0.20 = 24.5 MB
    // (< 38.5 MB proven safe; 43.7 MB failed)
    float*    Qn     = (float*)alloc((size_t)NN * CH * 4);
    unsigned* KVP    = (unsigned*)alloc((size_t)NN * CH * 4);
    int*      counts = (int*)alloc((size_t)NN * CSTR * 4);
    int2*     es     = (int2*)alloc((size_t)NN * SLOTS * 8);
    u16*      Wfrag  = (u16*)alloc((size_t)3 * 2 * 16384 * 2);

    hipMemsetAsync(counts, 0, (size_t)NN * CSTR * 4, stream);
    wprep_kernel<<<48, 256, 0, stream>>>(WQ, WK, WV, Wfrag);
    gemm_hist_kernel<<<GEMM_BLOCKS + HIST_BLOCKS, 256, 0, stream>>>(
        senders, receivers, Wfrag, Qn, KVP, eidx, counts, es);
    fused_kernel<<<NN / 4, 256, 0, stream>>>(es, counts, eattr, WE, att, Qn, KVP, out);
}

// Round 5
// 307.406 us; speedup vs baseline: 2.6726x; 2.6726x over previous
//
#include <hip/hip_runtime.h>

#define NN 10000
#define NE 640000
#define CH 128
#define NH 8
#define HD 16
#define BD 32
#define NEG 0.01f
#define SLOTS 160   // per-node edge-slot stride; deg ~ Poisson(64), P(>=160) ~ 1e-25
#define CSTR 32     // counts stride (ints): one counter per 128B (sector-safe)

#define GEMM_BLOCKS (NN / 16)            // 625 (16 rows per block)
#define HIST_BLOCKS 313                  // 8 edges per thread

typedef unsigned short u16;
using frag_ab = __attribute__((ext_vector_type(8))) short;  // 8 bf16 (4 VGPRs)
using frag_cd = __attribute__((ext_vector_type(4))) float;  // 4 fp32

// bf16 round-to-nearest-even
__device__ __forceinline__ u16 bf16h(float f) {
    unsigned b = __float_as_uint(f);
    b += 0x7fffu + ((b >> 16) & 1u);
    return (u16)(b >> 16);
}
__device__ __forceinline__ float bf2f(u16 h) {
    return __uint_as_float((unsigned)h << 16);
}

// DPP butterfly sum over each 16-lane row (one head = 16 channels): pure VALU.
template <int CTRL>
__device__ __forceinline__ float dpp_add(float x) {
    int v = __builtin_amdgcn_update_dpp(0, __float_as_int(x), CTRL, 0xF, 0xF, true);
    return x + __int_as_float(v);
}
__device__ __forceinline__ float sum16(float x) {
    x = dpp_add<0xB1>(x);   // quad_perm xor1
    x = dpp_add<0x4E>(x);   // quad_perm xor2
    x = dpp_add<0x141>(x);  // row_half_mirror
    x = dpp_add<0x140>(x);  // row_mirror
    return x;
}

// ---------------- K0: weight prep (48 blocks: 16 per matrix) -----------------
// Split W into bf16 hi/lo and pack into MFMA B-fragment order:
// Wfrag[(mat*2+hilo)*16384 + (nt*4+ks)*512 + lane*8 + i]
// where element (k,n): nt=n>>4, ks=k>>5, lane=((k&31)>>3)*16+(n&15), i=k&7.
__global__ __launch_bounds__(256) void wprep_kernel(
    const float* __restrict__ WQ, const float* __restrict__ WK,
    const float* __restrict__ WV, u16* __restrict__ Wfrag)
{
    int mat = blockIdx.x >> 4;
    int j0 = (blockIdx.x & 15) * 4;
    const float* W = mat == 0 ? WQ : (mat == 1 ? WK : WV);
    size_t mbase = (size_t)mat * 2 * 16384;
    int t = threadIdx.x;
    for (int j = j0; j < j0 + 4; ++j) {
        int lin = j * 256 + t;          // coalesced read
        int k = lin >> 7, n = lin & 127;
        float f = W[lin];
        u16 h = bf16h(f);
        u16 lo = bf16h(f - bf2f(h));
        int nt = n >> 4, ks = k >> 5, kk = k & 31;
        size_t o = (size_t)(nt * 4 + ks) * 512 + (size_t)(((kk >> 3) << 4) | (n & 15)) * 8 + (kk & 7);
        Wfrag[mbase + o] = h;
        Wfrag[mbase + 16384 + o] = lo;
    }
}

// ---------------- K1: hist + slot scatter (SEPARATE kernel for visibility) ---
// 8 edges/thread, int4 eidx loads, 8 independent returning-atomic chains;
// counts padded 1/128B (CSTR). Split from gemm so rocprof reports its own
// FETCH/WRITE/VALU: disambiguates returning-atomic serialization vs
// write-allocate scatter cost (R4 theory fork).
__global__ __launch_bounds__(256) void hist_kernel(
    const int* __restrict__ eidx, int* __restrict__ counts,
    int2* __restrict__ es)
{
    int t = blockIdx.x * 256 + threadIdx.x;
    int e0 = t * 8;
    if (e0 >= NE) return;
    int4 da = *(const int4*)(eidx + NE + e0);
    int4 db = *(const int4*)(eidx + NE + e0 + 4);
    int4 sa = *(const int4*)(eidx + e0);
    int4 sb = *(const int4*)(eidx + e0 + 4);
    int r0 = atomicAdd(&counts[da.x * CSTR], 1);
    int r1 = atomicAdd(&counts[da.y * CSTR], 1);
    int r2 = atomicAdd(&counts[da.z * CSTR], 1);
    int r3 = atomicAdd(&counts[da.w * CSTR], 1);
    int r4 = atomicAdd(&counts[db.x * CSTR], 1);
    int r5 = atomicAdd(&counts[db.y * CSTR], 1);
    int r6 = atomicAdd(&counts[db.z * CSTR], 1);
    int r7 = atomicAdd(&counts[db.w * CSTR], 1);
    es[da.x * SLOTS + r0] = make_int2(e0,     sa.x);
    es[da.y * SLOTS + r1] = make_int2(e0 + 1, sa.y);
    es[da.z * SLOTS + r2] = make_int2(e0 + 2, sa.z);
    es[da.w * SLOTS + r3] = make_int2(e0 + 3, sa.w);
    es[db.x * SLOTS + r4] = make_int2(e0 + 4, sb.x);
    es[db.y * SLOTS + r5] = make_int2(e0 + 5, sb.y);
    es[db.z * SLOTS + r6] = make_int2(e0 + 6, sb.z);
    es[db.w * SLOTS + r7] = make_int2(e0 + 7, sb.w);
}

// ---------------- K2: MFMA projections --------------------------------------
// 16 node-rows/block; wave w handles column tiles {2w,2w+1} for Q,K,V.
// fp32 exactness via 3-term bf16 split: Ah*Wh + Ah*Wl + Al*Wh.
__global__ __launch_bounds__(256) void gemm_kernel(
    const float* __restrict__ senders, const float* __restrict__ receivers,
    const u16* __restrict__ Wfrag,
    float* __restrict__ Qn, unsigned* __restrict__ KVP)
{
    int wave = threadIdx.x >> 6, l = threadIdx.x & 63;
    int r0 = blockIdx.x * 16;
    int arow = r0 + (l & 15);           // A-fragment row for this lane
    int kcol = (l >> 4) * 8;            // A-fragment k-offset within 32-k step

    // Load this strip's A rows (fp32) and split to bf16 hi/lo fragments.
    frag_ab Rh[4], Rl[4], Sh[4], Sl[4];
#pragma unroll
    for (int ks = 0; ks < 4; ++ks) {
        const float* rp = receivers + (size_t)arow * CH + ks * 32 + kcol;
        const float* sp = senders   + (size_t)arow * CH + ks * 32 + kcol;
        float4 ra = *(const float4*)rp, rb = *(const float4*)(rp + 4);
        float4 sa = *(const float4*)sp, sb = *(const float4*)(sp + 4);
        float rf[8] = {ra.x, ra.y, ra.z, ra.w, rb.x, rb.y, rb.z, rb.w};
        float sf[8] = {sa.x, sa.y, sa.z, sa.w, sb.x, sb.y, sb.z, sb.w};
#pragma unroll
        for (int i = 0; i < 8; ++i) {
            u16 rh = bf16h(rf[i]);  Rh[ks][i] = (short)rh;
            Rl[ks][i] = (short)bf16h(rf[i] - bf2f(rh));
            u16 sh = bf16h(sf[i]);  Sh[ks][i] = (short)sh;
            Sl[ks][i] = (short)bf16h(sf[i] - bf2f(sh));
        }
    }

    // W fragment loader: contiguous 16B per lane, fully coalesced, L2-hot.
    auto ldw = [&](int mat, int hilo, int nt, int ks) -> frag_ab {
        return *(const frag_ab*)(Wfrag + (size_t)(mat * 2 + hilo) * 16384
                                       + (size_t)(nt * 4 + ks) * 512 + l * 8);
    };

#pragma unroll
    for (int nts = 0; nts < 2; ++nts) {
        int nt = wave * 2 + nts;
        frag_cd aQ = {0.f, 0.f, 0.f, 0.f};
        frag_cd aK = {0.f, 0.f, 0.f, 0.f};
        frag_cd aV = {0.f, 0.f, 0.f, 0.f};
#pragma unroll
        for (int ks = 0; ks < 4; ++ks) {
            aQ = __builtin_amdgcn_mfma_f32_16x16x32_bf16(Rh[ks], ldw(0, 0, nt, ks), aQ, 0, 0, 0);
            aQ = __builtin_amdgcn_mfma_f32_16x16x32_bf16(Rh[ks], ldw(0, 1, nt, ks), aQ, 0, 0, 0);
            aQ = __builtin_amdgcn_mfma_f32_16x16x32_bf16(Rl[ks], ldw(0, 0, nt, ks), aQ, 0, 0, 0);
            aK = __builtin_amdgcn_mfma_f32_16x16x32_bf16(Sh[ks], ldw(1, 0, nt, ks), aK, 0, 0, 0);
            aK = __builtin_amdgcn_mfma_f32_16x16x32_bf16(Sh[ks], ldw(1, 1, nt, ks), aK, 0, 0, 0);
            aK = __builtin_amdgcn_mfma_f32_16x16x32_bf16(Sl[ks], ldw(1, 0, nt, ks), aK, 0, 0, 0);
            aV = __builtin_amdgcn_mfma_f32_16x16x32_bf16(Sh[ks], ldw(2, 0, nt, ks), aV, 0, 0, 0);
            aV = __builtin_amdgcn_mfma_f32_16x16x32_bf16(Sh[ks], ldw(2, 1, nt, ks), aV, 0, 0, 0);
            aV = __builtin_amdgcn_mfma_f32_16x16x32_bf16(Sl[ks], ldw(2, 0, nt, ks), aV, 0, 0, 0);
        }
        // D layout: col = lane&15, row = (lane>>4)*4 + j  [guide §3, m89-verified]
#pragma unroll
        for (int j = 0; j < 4; ++j) {
            int orow = r0 + (l >> 4) * 4 + j;
            int ocol = nt * 16 + (l & 15);
            size_t o = (size_t)orow * CH + ocol;
            Qn[o] = aQ[j];
            KVP[o] = (unsigned)bf16h(aK[j]) | ((unsigned)bf16h(aV[j]) << 16);
        }
    }
}

// ---------------- fused per-node edge loop (body UNCHANGED; 128-thr blocks) --
// One WAVE per node, lane l owns channels l and l+64. 8-edge tiles; eattr
// rows via wave-uniform s_load. KV gather: ONE dword per (edge, lane, half).
// Do not reshape this loop (R8/R9/R11 prev-session regressions; R1 edge-split
// regression; R4 (256,8) VGPR-32 spill regression: FETCH 159MB->1.66GB).
// 128-thread blocks (2 waves = 2 nodes), NO min-waves clause: compiler keeps
// natural ~48 VGPR (no spill), HW fits up to 16 WGs/CU -> 32 waves/CU
// (vs 13 resident at 256-thr/4-WG). Occupancy was the 60% idle (R3 model:
// ~80us VALU issue floor + latency not hidden at 3.2 waves/SIMD).
__global__ __launch_bounds__(128) void fused_kernel(
    const int2* __restrict__ es, const int* __restrict__ counts,
    const float* __restrict__ eattr, const float* __restrict__ WE,
    const float* __restrict__ att, const float* __restrict__ Qn,
    const unsigned* __restrict__ KVP, float* __restrict__ out)
{
    int wave = threadIdx.x >> 6, l = threadIdx.x & 63;
    int n = blockIdx.x * 2 + wave;            // 5000 blocks * 2 waves = NN
    int start = n * SLOTS;
    int end = start + counts[n * CSTR];

    float rWE[2 * BD];
#pragma unroll
    for (int k = 0; k < BD; ++k) {
        rWE[k]      = WE[k * CH + l];
        rWE[BD + k] = WE[k * CH + 64 + l];
    }
#pragma unroll
    for (int k = 0; k < 2 * BD; ++k) asm volatile("" : "+v"(rWE[k]));

    float a0 = att[l], a1 = att[64 + l];
    float q0 = Qn[(size_t)n * CH + l], q1 = Qn[(size_t)n * CH + 64 + l];
    float acc0 = 0.f, acc1 = 0.f, sum0 = 0.f, sum1 = 0.f;

    for (int base = start; base < end; base += 8) {
        int m = end - base;                   // >=1
        int idx = base + (l & 7);
        if (idx >= end) idx = end - 1;
        int2 esv = es[idx];
#pragma unroll 8
        for (int t = 0; t < 8; ++t) {
            if (t >= m) break;                // wave-uniform
            int e   = __builtin_amdgcn_readlane(esv.x, t);
            int src = __builtin_amdgcn_readlane(esv.y, t);
            const float* __restrict__ row = eattr + (size_t)e * BD;
            size_t so = (size_t)src * CH;
            unsigned p0 = KVP[so + l];
            unsigned p1 = KVP[so + 64 + l];
            float kb0 = __uint_as_float(p0 << 16);
            float kb1 = __uint_as_float(p1 << 16);
            float vv0 = __uint_as_float(p0 & 0xffff0000u);
            float vv1 = __uint_as_float(p1 & 0xffff0000u);
            float ec0 = 0.f, ec1 = 0.f;
#pragma unroll
            for (int k = 0; k < BD; ++k) {
                float rv = row[k];            // uniform -> s_load
                ec0 = fmaf(rv, rWE[k],      ec0);
                ec1 = fmaf(rv, rWE[BD + k], ec1);
            }
            float h0 = q0 + kb0 + ec0; h0 = h0 > 0.f ? h0 : NEG * h0;
            float h1 = q1 + kb1 + ec1; h1 = h1 > 0.f ? h1 : NEG * h1;
            float t0 = sum16(a0 * h0);
            float t1 = sum16(a1 * h1);
            float e0 = __expf(t0), e1 = __expf(t1);
            sum0 += e0; acc0 = fmaf(e0, vv0, acc0);
            sum1 += e1; acc1 = fmaf(e1, vv1, acc1);
        }
    }
    out[(size_t)n * CH + l]      = (end > start) ? acc0 / sum0 : 0.f;
    out[(size_t)n * CH + 64 + l] = (end > start) ? acc1 / sum1 : 0.f;
}

extern "C" void kernel_launch(void* const* d_in, const int* in_sizes, int n_in,
                              void* d_out, int out_size, void* d_ws, size_t ws_size,
                              hipStream_t stream)
{
    const float* senders   = (const float*)d_in[0];
    const float* receivers = (const float*)d_in[1];
    const int*   eidx      = (const int*)d_in[2];
    const float* eattr     = (const float*)d_in[3];
    const float* WQ  = (const float*)d_in[4];
    const float* WK  = (const float*)d_in[5];
    const float* WV  = (const float*)d_in[6];
    const float* WE  = (const float*)d_in[7];
    const float* att = (const float*)d_in[8];
    float* out = (float*)d_out;

    char* ws = (char*)d_ws;
    size_t off = 0;
    auto alloc = [&](size_t bytes) -> void* {
        void* p = ws + off;
        off += (bytes + 255) & ~(size_t)255;
        return p;
    };
    // Qn 5.12 + KVP 5.12 + counts 1.28 + es 12.8 + Wfrag 0.20 = 24.5 MB
    // (< 38.5 MB proven safe; 43.7 MB failed)
    float*    Qn     = (float*)alloc((size_t)NN * CH * 4);
    unsigned* KVP    = (unsigned*)alloc((size_t)NN * CH * 4);
    int*      counts = (int*)alloc((size_t)NN * CSTR * 4);
    int2*     es     = (int2*)alloc((size_t)NN * SLOTS * 8);
    u16*      Wfrag  = (u16*)alloc((size_t)3 * 2 * 16384 * 2);

    hipMemsetAsync(counts, 0, (size_t)NN * CSTR * 4, stream);
    hist_kernel<<<HIST_BLOCKS, 256, 0, stream>>>(eidx, counts, es);
    wprep_kernel<<<48, 256, 0, stream>>>(WQ, WK, WV, Wfrag);
    gemm_kernel<<<GEMM_BLOCKS, 256, 0, stream>>>(
        senders, receivers, Wfrag, Qn, KVP);
    fused_kernel<<<NN / 2, 128, 0, stream>>>(es, counts, eattr, WE, att, Qn, KVP, out);
}